// Round 13
// baseline (179.389 us; speedup 1.0000x reference)
//
#include <hip/hip_runtime.h>
#include <math.h>

// Problem constants: B=2, S=2048, E=1024, NH=16, hd=64, T=1 (seq = S)
#define BB 2
#define SS 2048
#define EE 1024
#define NHH 16
#define HD 64
#define HD2 32

typedef _Float16 f16x8 __attribute__((ext_vector_type(8)));   // 8 f16 = 4 VGPRs
typedef __fp16 fp16x2 __attribute__((ext_vector_type(2)));    // cvt_pkrtz result
typedef __attribute__((ext_vector_type(4))) float f32x4;      // MFMA accumulator

// pack two fp32 -> half2 with RNE (v_cvt_f16_f32 x2 + pack)
static __device__ __forceinline__ unsigned pkh(float a, float b) {
    union { _Float16 h[2]; unsigned u; } v;
    v.h[0] = (_Float16)a; v.h[1] = (_Float16)b;
    return v.u;
}

// pack two fp32 -> half2 with RTZ, single v_cvt_pkrtz_f16_f32
static __device__ __forceinline__ unsigned pkrtz(float a, float b) {
    union { fp16x2 h2; unsigned u; } v;
    v.h2 = __builtin_amdgcn_cvt_pkrtz(a, b);
    return v.u;
}

// ---- async global->LDS DMA, 16B per lane (global_load_lds_dwordx4) ----
static __device__ __forceinline__ void dma16(const void* g, void* l) {
    __builtin_amdgcn_global_load_lds(
        (const __attribute__((address_space(1))) unsigned int*)g,
        (__attribute__((address_space(3))) unsigned int*)l,
        16, 0, 0);
}

// ---------------- kernel 1: RoPE tables + fp32 -> f16 pre-convert --------
// Merged launch: blocks [0,256) build the cos/sin tables; blocks [256, 3840)
// do the LDS-tile-order f16 conversion (saves one kernel launch).
#define NXCHUNK 524288    // 4096*1024/8
#define NWCHUNK 393216    // 3072*1024/8
__global__ __launch_bounds__(256) void tabcvt_k(
    const float* __restrict__ X, const float* __restrict__ W,
    unsigned short* __restrict__ Xh, unsigned short* __restrict__ Wh,
    float* __restrict__ ct, float* __restrict__ st)
{
    int bid = blockIdx.x;
    if (bid < 256) {
        int idx = bid * 256 + threadIdx.x;   // idx = s*32 + p, < 65536 exact
        int s = idx >> 5, p = idx & 31;
        double inv = pow(10000.0, -(double)(2 * p) / 64.0);
        double ang = (double)s * inv;
        ct[idx] = (float)cos(ang);
        st[idx] = (float)sin(ang);
        return;
    }
    int idx = (bid - 256) * 256 + threadIdx.x;
    const float* src;
    unsigned short* dst;
    int c;
    if (idx < NXCHUNK) { src = X; dst = Xh; c = idx; }
    else               { src = W; dst = Wh; c = idx - NXCHUNK;
                         if (c >= NWCHUNK) return; }
    int l15 = c & 15, q = (c >> 4) & 3, grp = (c >> 6) & 7;
    int kt = (c >> 9) & 31, t = c >> 14;
    int row = t * 128 + grp * 16 + l15;
    int k   = kt * 32 + q * 8;
    float4 v0 = *(const float4*)(src + (size_t)row * EE + k);
    float4 v1 = *(const float4*)(src + (size_t)row * EE + k + 4);
    *(uint4*)(dst + (size_t)c * 8) =
        make_uint4(pkh(v0.x, v0.y), pkh(v0.z, v0.w), pkh(v1.x, v1.y), pkh(v1.z, v1.w));
}

// ---------------- kernel 2: QKV GEMM (f16, A-LDS + B-direct) -------------
// r22: B (W) fragments read DIRECTLY from global -- Wh is L2-resident per
// XCD (768 KB < 4 MB) and cvt wrote it in exact fragment order, so
// Bf[nc] = lane-contiguous 1KB global load (identical bytes to the old
// LDS path). Deletes 2 dma16 + 4 ds_read_b128 per wave-step; barrier now
// protects only the 8 KB A dbuf; compiler can pipeline B loads across
// K-steps. 64x128 tile, grid 1536 = 6 blocks/CU, 6 waves/SIMD.
__global__ __launch_bounds__(256, 6) void qkv_mfma_k(
    const unsigned short* __restrict__ Xh, const unsigned short* __restrict__ Wh,
    const float* __restrict__ bias,
    const float* __restrict__ ct, const float* __restrict__ st,
    unsigned short* __restrict__ Qg, unsigned short* __restrict__ Kg,
    unsigned short* __restrict__ Vg)
{
    __shared__ __align__(16) unsigned short Alds[2][2048];   // 2 x 4 KB (64x32)

    const int tid  = threadIdx.x;
    const int wave = tid >> 6;
    const int lane = tid & 63;
    const int quad = lane >> 4;
    const int l15  = lane & 15;

    // XCD-pinned decode: 1536 blocks, id&7 = XCD, 192/XCD = 3 nt x 64 mt
    const int id    = blockIdx.x;
    const int xcd   = id & 7;
    const int local = id >> 3;
    const int nt    = xcd * 3 + local % 3;
    const int mt    = local / 3;            // 0..63, 64-row tiles
    const int m0    = mt * 64;
    const int n0b   = nt * 128;

    f32x4 acc[2][4];
#pragma unroll
    for (int mc = 0; mc < 2; mc++)
#pragma unroll
        for (int nc = 0; nc < 4; nc++) acc[mc][nc] = (f32x4){0.f, 0.f, 0.f, 0.f};

    const int wr = wave >> 1;          // 0..1: m-half of the 64 rows
    const int wc = wave & 1;           // 0..1: n-half of the 128 cols

    // A source: (t = mt>>1, kt) supertile is 4096 shorts; half (mt&1) is a
    // contiguous 2048-short run (grp 0-3 = rows t*128..+63, grp 4-7 = +64..127)
    const size_t ab0 = ((size_t)(mt >> 1) * 32) * 4096 + (size_t)(mt & 1) * 2048;
    // per-lane B fragment base: advances 4096 elems per K-step, nc*512 imm
    const unsigned short* wb = Wh + ((size_t)nt * 32) * 4096 +
                               ((wc * 4) * 4 + quad) * 128 + l15 * 8;

    // prologue: stage A kt=0 into buffer 0 (4 KB = 1 dma16/thread)
    dma16(Xh + ab0 + (size_t)tid * 8, &Alds[0][tid * 8]);
    __syncthreads();

    int cur = 0;
    for (int kt = 0; kt < EE / 32; kt++) {
        if (kt + 1 < EE / 32) {
            const unsigned short* at = Xh + ab0 + (size_t)(kt + 1) * 4096;
            dma16(at + (size_t)tid * 8, &Alds[cur ^ 1][tid * 8]);
        }

        // B fragments straight from L2-resident Wh (lane-contiguous 1KB)
        f16x8 Af[2], Bf[4];
#pragma unroll
        for (int nc = 0; nc < 4; nc++)
            Bf[nc] = *(const f16x8*)(wb + nc * 512);
#pragma unroll
        for (int mc = 0; mc < 2; mc++)
            Af[mc] = *(const f16x8*)(&Alds[cur][((wr * 2 + mc) * 4 + quad) * 128 + l15 * 8]);
#pragma unroll
        for (int mc = 0; mc < 2; mc++)
#pragma unroll
            for (int nc = 0; nc < 4; nc++)
                acc[mc][nc] = __builtin_amdgcn_mfma_f32_16x16x32_f16(Af[mc], Bf[nc], acc[mc][nc], 0, 0, 0);

        __syncthreads();   // waves done reading Alds[cur]; prefetch drained
        cur ^= 1;
        wb += 4096;
    }

    // ---- epilogue: bias + RoPE + f16 RNE pack + swizzled scatter ----
    const int n0w = n0b + wc * 64;
    const int m0w = m0 + wr * 32;          // 32 rows per wave
    const int sec = n0w >> 10;
    const int h   = (n0w & 1023) >> 6;
    const int bq  = m0w >> 11;
    const size_t abase = (size_t)(bq * NHH + h) * 131072;
    unsigned short* dst = (sec == 0) ? Qg : (sec == 1) ? Kg : Vg;

    float bn[4];
#pragma unroll
    for (int nc = 0; nc < 4; nc++) bn[nc] = bias[n0w + nc * 16 + l15];

    if (sec < 2) {
        // Q gets 0.125 * log2(e) so attention softmax can use exp2 directly
        const float scq = (sec == 0) ? 0.18033688f : 1.0f;
#pragma unroll
        for (int mc = 0; mc < 2; mc++) {
            int sb = (m0w & 2047) + mc * 16;
#pragma unroll
            for (int nc = 0; nc < 4; nc++) {
                int d = nc * 16 + l15;
                int p = d >> 1;
                int kc_d = d >> 5, quad_a = (d >> 3) & 3, j = d & 7;
#pragma unroll
                for (int rr = 0; rr < 4; rr++) {
                    int srow = sb + quad * 4 + rr;
                    float x = acc[mc][nc][rr] + bn[nc];
                    float xp = __shfl_xor(x, 1);
                    float c = ct[srow * 32 + p], sn = st[srow * 32 + p];
                    float o = ((l15 & 1) == 0) ? (x * c - xp * sn) : (xp * sn + x * c);
                    o *= scq;
                    float op = __shfl_xor(o, 1);
                    if ((l15 & 1) == 0) {
                        unsigned u = pkh(o, op);   // (d, d+1) halves
                        size_t e;
                        if (sec == 0) {
                            // Q: B-operand layout (unchanged)
                            e = abase +
                                (size_t)((((srow >> 4) * 2 + kc_d) * 4 + quad_a)) * 128 +
                                (srow & 15) * 8 + j;
                        } else {
                            // K: kappa-permuted A-block layout (r15, verified)
                            int key6 = srow & 63;
                            int mc_k = ((key6 >> 4) & 2) | ((key6 >> 2) & 1);
                            int l15k = ((key6 >> 1) & 12) | (key6 & 3);
                            e = abase + (size_t)(srow >> 6) * 4096 +
                                (mc_k * 2 + kc_d) * 512 + (quad_a * 16 + l15k) * 8 + j;
                        }
                        *(unsigned int*)(dst + e) = u;
                    }
                }
            }
        }
    } else {
        // V: fragment-major per 64-key tile (r16, verified)
#pragma unroll
        for (int mc = 0; mc < 2; mc++) {
            int key   = (m0w & 2047) + mc * 16 + quad * 4;   // rr=0 key
            int tile  = key >> 6;
            int kk2v  = (key >> 5) & 1;
            int quadk = ((key >> 3) & 3);
            int j0    = (quad & 1) * 4;
#pragma unroll
            for (int nc = 0; nc < 4; nc++) {
                float x0 = acc[mc][nc][0] + bn[nc];
                float x1 = acc[mc][nc][1] + bn[nc];
                float x2 = acc[mc][nc][2] + bn[nc];
                float x3 = acc[mc][nc][3] + bn[nc];
                unsigned u01 = pkh(x0, x1), u23 = pkh(x2, x3);
                size_t e = abase + (size_t)tile * 4096 +
                           (size_t)(((nc * 2 + kk2v) * 4 + quadk)) * 128 + l15 * 8 + j0;
                *(uint2*)(dst + e) = make_uint2(u01, u23);
            }
        }
    }
}

// ---------------- kernel 3: flash attention, f16 MFMA -------------------
// r21 state (unchanged): in-register P (kappa-K), fragment-major V,
// ones-MFMA row-sum, pkrtz pack, shfl-free defer-max vote, KVBLK=128
// dbuf, one barrier per 128 keys, LDS 32 KB, 4 blocks/CU.
__global__ __launch_bounds__(256, 4) void attn_mfma_k(
    const unsigned short* __restrict__ Qg,
    const unsigned short* __restrict__ Kg,
    const unsigned short* __restrict__ Vg,
    float* __restrict__ out)
{
    __shared__ __align__(16) unsigned short Klds[2][8192];   // K dbuf: 32 KB

    const int tid  = threadIdx.x;
    const int wave = tid >> 6;
    const int lane = tid & 63;
    const int quad = lane >> 4;
    const int l15  = lane & 15;
    const int id   = blockIdx.x;
    const int bh   = (id & 7) * 4 + ((id >> 3) & 3);   // XCD-pinned bh
    const int qt   = id >> 5;
    const int b    = bh >> 4, h = bh & 15;
    const int q0   = qt * 64 + wave * 16;
    const size_t abase = (size_t)bh * 131072;

    // Q fragments: 16 q rows per wave (B-operand, col = l15 = q)
    f16x8 qf[2];
#pragma unroll
    for (int kc = 0; kc < 2; kc++)
        qf[kc] = *(const f16x8*)(Qg + abase +
            (size_t)((((q0 >> 4) * 2 + kc) * 4 + quad)) * 128 + l15 * 8);

    // all-ones B fragment for the ps row-sum MFMA
    f16x8 ones;
#pragma unroll
    for (int i = 0; i < 8; i++) ones[i] = (_Float16)1.0f;

    f32x4 acc[4];
#pragma unroll
    for (int dc = 0; dc < 4; dc++) acc[dc] = (f32x4){0.f, 0.f, 0.f, 0.f};
    float mst = -INFINITY;
    f32x4 lst4 = (f32x4){0.f, 0.f, 0.f, 0.f};   // acc-row layout: q = quad*4+rr

    const unsigned short* kgb = Kg + abase;
    // V (fragment-major): lane base + (dc*2+kk2)*512 elem imm offsets.
    const unsigned short* vt0 = Vg + abase + quad * 128 + l15 * 8;
    const unsigned short* vt1 = vt0 + 2048;

    // one 64-key sub-tile, P never leaves registers
    auto process64 = [&](const unsigned short* ktile) {
        // V fragments (B-operand), lane-contiguous coalesced loads
        f16x8 vf[4][2];
#pragma unroll
        for (int dc = 0; dc < 2; dc++) {
            vf[dc][0]     = *(const f16x8*)(vt0 + dc * 1024);
            vf[dc][1]     = *(const f16x8*)(vt0 + dc * 1024 + 512);
            vf[dc + 2][0] = *(const f16x8*)(vt1 + dc * 1024);
            vf[dc + 2][1] = *(const f16x8*)(vt1 + dc * 1024 + 512);
        }

        // QK^T from kappa-permuted K blocks: read = base + lane*16B + imm
        const unsigned short* kb = ktile + lane * 8;
        f32x4 stt[4];
        __builtin_amdgcn_s_setprio(1);
#pragma unroll
        for (int mc = 0; mc < 4; mc++) {
            f16x8 a0 = *(const f16x8*)(kb + mc * 1024);
            f16x8 a1 = *(const f16x8*)(kb + mc * 1024 + 512);
            f32x4 s = (f32x4){0.f, 0.f, 0.f, 0.f};
            s = __builtin_amdgcn_mfma_f32_16x16x32_f16(a0, qf[0], s, 0, 0, 0);
            s = __builtin_amdgcn_mfma_f32_16x16x32_f16(a1, qf[1], s, 0, 0, 0);
            stt[mc] = s;
        }
        __builtin_amdgcn_s_setprio(0);

        // per-lane LOCAL max, balanced tree (no cross-lane shfl here)
        float t0 = fmaxf(fmaxf(stt[0][0], stt[0][1]), fmaxf(stt[0][2], stt[0][3]));
        float t1 = fmaxf(fmaxf(stt[1][0], stt[1][1]), fmaxf(stt[1][2], stt[1][3]));
        float t2 = fmaxf(fmaxf(stt[2][0], stt[2][1]), fmaxf(stt[2][2], stt[2][3]));
        float t3 = fmaxf(fmaxf(stt[3][0], stt[3][1]), fmaxf(stt[3][2], stt[3][3]));
        float mtl = fmaxf(fmaxf(t0, t1), fmaxf(t2, t3));

        // defer-max vote on the LOCAL max: equivalent outcome to the
        // cross-lane version, zero shfl in the common path
        if (!__all(mtl - mst <= 8.f)) {
            // rare path: full cross-lane reduce + rescale
            float mt = fmaxf(mtl, __shfl_xor(mtl, 16));
            mt = fmaxf(mt, __shfl_xor(mt, 32));
            float mnew = fmaxf(mst, mt);
            float alpha = __builtin_amdgcn_exp2f(mst - mnew);
            float ar[4];
#pragma unroll
            for (int rr = 0; rr < 4; rr++)
                ar[rr] = __shfl(alpha, (lane & 48) + ((lane >> 4) << 2) + rr);
#pragma unroll
            for (int rr = 0; rr < 4; rr++) lst4[rr] *= ar[rr];
#pragma unroll
            for (int dc = 0; dc < 4; dc++)
#pragma unroll
                for (int rr = 0; rr < 4; rr++) acc[dc][rr] *= ar[rr];
            mst = mnew;
        }

        // P = exp2(S - mst), pack f16 in-register via cvt_pkrtz (these
        // words ARE the PV A-fragments thanks to the kappa-permuted K)
        unsigned up[4][2];
#pragma unroll
        for (int mc = 0; mc < 4; mc++) {
            float e0 = __builtin_amdgcn_exp2f(stt[mc][0] - mst);
            float e1 = __builtin_amdgcn_exp2f(stt[mc][1] - mst);
            float e2 = __builtin_amdgcn_exp2f(stt[mc][2] - mst);
            float e3 = __builtin_amdgcn_exp2f(stt[mc][3] - mst);
            up[mc][0] = pkrtz(e0, e1);
            up[mc][1] = pkrtz(e2, e3);
        }

        union { unsigned u[4]; f16x8 h; } pc0, pc1;
        pc0.u[0] = up[0][0]; pc0.u[1] = up[0][1];
        pc0.u[2] = up[1][0]; pc0.u[3] = up[1][1];
        pc1.u[0] = up[2][0]; pc1.u[1] = up[2][1];
        pc1.u[2] = up[3][0]; pc1.u[3] = up[3][1];

        __builtin_amdgcn_s_setprio(1);
        // ps row-sum on the matrix pipe: lst4 += P . ones (acc-row layout)
        {
            f32x4 psa = (f32x4){0.f, 0.f, 0.f, 0.f};
            psa = __builtin_amdgcn_mfma_f32_16x16x32_f16(pc0.h, ones, psa, 0, 0, 0);
            psa = __builtin_amdgcn_mfma_f32_16x16x32_f16(pc1.h, ones, psa, 0, 0, 0);
            lst4 += psa;
        }
#pragma unroll
        for (int dc = 0; dc < 4; dc++) {
            f32x4 aa = acc[dc];
            aa = __builtin_amdgcn_mfma_f32_16x16x32_f16(pc0.h, vf[dc][0], aa, 0, 0, 0);
            aa = __builtin_amdgcn_mfma_f32_16x16x32_f16(pc1.h, vf[dc][1], aa, 0, 0, 0);
            acc[dc] = aa;
        }
        __builtin_amdgcn_s_setprio(0);

        vt0 += 4096;
        vt1 += 4096;
    };

    // prologue: stage K tile 0 (128 keys, 16 KB)
#pragma unroll
    for (int i = 0; i < 4; i++)
        dma16(kgb + (size_t)(tid + i * 256) * 8, &Klds[0][(tid + i * 256) * 8]);
    __syncthreads();

    int cur = 0;
    for (int it = 0; it < SS / 128; it++) {
        // prefetch next 128-key tile into the other buffer
        if (it + 1 < SS / 128) {
            const unsigned short* ks = kgb + (size_t)(it + 1) * 8192;
#pragma unroll
            for (int i = 0; i < 4; i++)
                dma16(ks + (size_t)(tid + i * 256) * 8,
                      &Klds[cur ^ 1][(tid + i * 256) * 8]);
        }

        process64(&Klds[cur][0]);
        process64(&Klds[cur][4096]);

        __syncthreads();   // all waves done with Klds[cur]; prefetch drained
        cur ^= 1;
    }

    // lst4 is already in acc-row layout: no shuffle needed
    float linv[4];
#pragma unroll
    for (int rr = 0; rr < 4; rr++) linv[rr] = 1.f / lst4[rr];
#pragma unroll
    for (int dc = 0; dc < 4; dc++)
#pragma unroll
        for (int rr = 0; rr < 4; rr++) {
            int s = q0 + quad * 4 + rr;
            out[((size_t)(b * SS + s)) * EE + h * HD + dc * 16 + l15] = acc[dc][rr] * linv[rr];
        }
}

extern "C" void kernel_launch(void* const* d_in, const int* in_sizes, int n_in,
                              void* d_out, int out_size, void* d_ws, size_t ws_size,
                              hipStream_t stream) {
    const float* X    = (const float*)d_in[0];
    const float* W    = (const float*)d_in[1];
    const float* bias = (const float*)d_in[2];
    float* out = (float*)d_out;

    float* ws = (float*)d_ws;
    float* ct = ws;                    // 65536 f32
    float* st = ws + 65536;            // 65536 f32
    unsigned short* base = (unsigned short*)(ws + 131072);
    const size_t ASZ = (size_t)32 * 131072;   // 4.19M f16 per array
    unsigned short* Qg = base;
    unsigned short* Kg = base + ASZ;
    unsigned short* Vg = base + 2 * ASZ;
    unsigned short* Xh = base + 3 * ASZ;              // 4.19M f16 (8.4 MB)
    unsigned short* Wh = Xh + (size_t)NXCHUNK * 8;    // 3.15M f16 (6.3 MB)

    tabcvt_k<<<dim3(256 + (NXCHUNK + NWCHUNK) / 256), 256, 0, stream>>>(
        X, W, Xh, Wh, ct, st);
    qkv_mfma_k<<<dim3(1536), 256, 0, stream>>>(
        Xh, Wh, bias, ct, st, Qg, Kg, Vg);
    attn_mfma_k<<<dim3(1024), 256, 0, stream>>>(Qg, Kg, Vg, out);
}

// Round 14
// 175.229 us; speedup vs baseline: 1.0237x; 1.0237x over previous
//
#include <hip/hip_runtime.h>
#include <math.h>

// Problem constants: B=2, S=2048, E=1024, NH=16, hd=64, T=1 (seq = S)
#define BB 2
#define SS 2048
#define EE 1024
#define NHH 16
#define HD 64
#define HD2 32

typedef _Float16 f16x8 __attribute__((ext_vector_type(8)));   // 8 f16 = 4 VGPRs
typedef __fp16 fp16x2 __attribute__((ext_vector_type(2)));    // cvt_pkrtz result
typedef __attribute__((ext_vector_type(4))) float f32x4;      // MFMA accumulator

// pack two fp32 -> half2 with RNE (v_cvt_f16_f32 x2 + pack)
static __device__ __forceinline__ unsigned pkh(float a, float b) {
    union { _Float16 h[2]; unsigned u; } v;
    v.h[0] = (_Float16)a; v.h[1] = (_Float16)b;
    return v.u;
}

// pack two fp32 -> half2 with RTZ, single v_cvt_pkrtz_f16_f32
static __device__ __forceinline__ unsigned pkrtz(float a, float b) {
    union { fp16x2 h2; unsigned u; } v;
    v.h2 = __builtin_amdgcn_cvt_pkrtz(a, b);
    return v.u;
}

// ---- async global->LDS DMA, 16B per lane (global_load_lds_dwordx4) ----
static __device__ __forceinline__ void dma16(const void* g, void* l) {
    __builtin_amdgcn_global_load_lds(
        (const __attribute__((address_space(1))) unsigned int*)g,
        (__attribute__((address_space(3))) unsigned int*)l,
        16, 0, 0);
}

// ---------------- kernel 1: RoPE tables + fp32 -> f16 pre-convert --------
// Merged launch: blocks [0,256) build the cos/sin tables; blocks [256, 3840)
// do the LDS-tile-order f16 conversion (saves one kernel launch).
#define NXCHUNK 524288    // 4096*1024/8
#define NWCHUNK 393216    // 3072*1024/8
__global__ __launch_bounds__(256) void tabcvt_k(
    const float* __restrict__ X, const float* __restrict__ W,
    unsigned short* __restrict__ Xh, unsigned short* __restrict__ Wh,
    float* __restrict__ ct, float* __restrict__ st)
{
    int bid = blockIdx.x;
    if (bid < 256) {
        int idx = bid * 256 + threadIdx.x;   // idx = s*32 + p, < 65536 exact
        int s = idx >> 5, p = idx & 31;
        double inv = pow(10000.0, -(double)(2 * p) / 64.0);
        double ang = (double)s * inv;
        ct[idx] = (float)cos(ang);
        st[idx] = (float)sin(ang);
        return;
    }
    int idx = (bid - 256) * 256 + threadIdx.x;
    const float* src;
    unsigned short* dst;
    int c;
    if (idx < NXCHUNK) { src = X; dst = Xh; c = idx; }
    else               { src = W; dst = Wh; c = idx - NXCHUNK;
                         if (c >= NWCHUNK) return; }
    int l15 = c & 15, q = (c >> 4) & 3, grp = (c >> 6) & 7;
    int kt = (c >> 9) & 31, t = c >> 14;
    int row = t * 128 + grp * 16 + l15;
    int k   = kt * 32 + q * 8;
    float4 v0 = *(const float4*)(src + (size_t)row * EE + k);
    float4 v1 = *(const float4*)(src + (size_t)row * EE + k + 4);
    *(uint4*)(dst + (size_t)c * 8) =
        make_uint4(pkh(v0.x, v0.y), pkh(v0.z, v0.w), pkh(v1.x, v1.y), pkh(v1.z, v1.w));
}

// ---------------- kernel 2: QKV GEMM (f16, dma16-staged, dbuf) -----------
// r23: 128x128 tile @ 512 threads / 8 waves (each wave the same 32x64
// sub-tile as r17 -> per-wave code identical). Grid 768 = 3 blocks/CU x
// 8 waves = 6 waves/SIMD (same occupancy as r17) but block-distinct
// staging traffic drops 72 -> 48 KB per CU-kstep (-33%) and dma16s per
// thread-kstep 3 -> 2. Single barrier per K-step, dbuf. XCD-pinned:
// 3 nt per XCD (W set 768 KB f16 L2-resident). B dedup restored (r22's
// B-direct raised L2 traffic and was neutral-to-negative).
__global__ __launch_bounds__(512, 6) void qkv_mfma_k(
    const unsigned short* __restrict__ Xh, const unsigned short* __restrict__ Wh,
    const float* __restrict__ bias,
    const float* __restrict__ ct, const float* __restrict__ st,
    unsigned short* __restrict__ Qg, unsigned short* __restrict__ Kg,
    unsigned short* __restrict__ Vg)
{
    __shared__ __align__(16) unsigned short Alds[2][4096];   // 2 x 8 KB (128x32)
    __shared__ __align__(16) unsigned short Blds[2][4096];   // 2 x 8 KB (128x32)

    const int tid  = threadIdx.x;
    const int wave = tid >> 6;          // 0..7
    const int lane = tid & 63;
    const int quad = lane >> 4;
    const int l15  = lane & 15;

    // XCD-pinned decode: 768 blocks, id&7 = XCD, 96/XCD = 3 nt x 32 mt
    const int id    = blockIdx.x;
    const int xcd   = id & 7;
    const int local = id >> 3;
    const int nt    = xcd * 3 + local % 3;
    const int mt    = local / 3;            // 0..31, 128-row tiles
    const int n0b   = nt * 128;

    f32x4 acc[2][4];
#pragma unroll
    for (int mc = 0; mc < 2; mc++)
#pragma unroll
        for (int nc = 0; nc < 4; nc++) acc[mc][nc] = (f32x4){0.f, 0.f, 0.f, 0.f};

    const int wr = wave >> 1;          // 0..3: 32-row slice
    const int wc = wave & 1;           // 0..1: 64-col slice

    const size_t ab0 = ((size_t)(mt * 32)) * 4096;   // Xh supertile base
    const size_t bb0 = ((size_t)(nt * 32)) * 4096;

    // prologue: stage kt=0 into buffer 0 (8 KB each = 1 dma16/thread)
    dma16(Xh + ab0 + (size_t)tid * 8, &Alds[0][tid * 8]);
    dma16(Wh + bb0 + (size_t)tid * 8, &Blds[0][tid * 8]);
    __syncthreads();

    int cur = 0;
    for (int kt = 0; kt < EE / 32; kt++) {
        if (kt + 1 < EE / 32) {
            const unsigned short* at = Xh + ab0 + (size_t)(kt + 1) * 4096;
            const unsigned short* bt = Wh + bb0 + (size_t)(kt + 1) * 4096;
            dma16(at + (size_t)tid * 8, &Alds[cur ^ 1][tid * 8]);
            dma16(bt + (size_t)tid * 8, &Blds[cur ^ 1][tid * 8]);
        }

        f16x8 Af[2], Bf[4];
#pragma unroll
        for (int mc = 0; mc < 2; mc++)
            Af[mc] = *(const f16x8*)(&Alds[cur][((wr * 2 + mc) * 4 + quad) * 128 + l15 * 8]);
#pragma unroll
        for (int nc = 0; nc < 4; nc++)
            Bf[nc] = *(const f16x8*)(&Blds[cur][((wc * 4 + nc) * 4 + quad) * 128 + l15 * 8]);
#pragma unroll
        for (int mc = 0; mc < 2; mc++)
#pragma unroll
            for (int nc = 0; nc < 4; nc++)
                acc[mc][nc] = __builtin_amdgcn_mfma_f32_16x16x32_f16(Af[mc], Bf[nc], acc[mc][nc], 0, 0, 0);

        __syncthreads();   // waves done reading buf[cur]; prefetch drained
        cur ^= 1;
    }

    // ---- epilogue: bias + RoPE + f16 RNE pack + swizzled scatter ----
    const int n0w = n0b + wc * 64;
    const int m0w = mt * 128 + wr * 32;    // 32 rows per wave
    const int sec = n0w >> 10;
    const int h   = (n0w & 1023) >> 6;
    const int bq  = m0w >> 11;
    const size_t abase = (size_t)(bq * NHH + h) * 131072;
    unsigned short* dst = (sec == 0) ? Qg : (sec == 1) ? Kg : Vg;

    float bn[4];
#pragma unroll
    for (int nc = 0; nc < 4; nc++) bn[nc] = bias[n0w + nc * 16 + l15];

    if (sec < 2) {
        // Q gets 0.125 * log2(e) so attention softmax can use exp2 directly
        const float scq = (sec == 0) ? 0.18033688f : 1.0f;
#pragma unroll
        for (int mc = 0; mc < 2; mc++) {
            int sb = (m0w & 2047) + mc * 16;
#pragma unroll
            for (int nc = 0; nc < 4; nc++) {
                int d = nc * 16 + l15;
                int p = d >> 1;
                int kc_d = d >> 5, quad_a = (d >> 3) & 3, j = d & 7;
#pragma unroll
                for (int rr = 0; rr < 4; rr++) {
                    int srow = sb + quad * 4 + rr;
                    float x = acc[mc][nc][rr] + bn[nc];
                    float xp = __shfl_xor(x, 1);
                    float c = ct[srow * 32 + p], sn = st[srow * 32 + p];
                    float o = ((l15 & 1) == 0) ? (x * c - xp * sn) : (xp * sn + x * c);
                    o *= scq;
                    float op = __shfl_xor(o, 1);
                    if ((l15 & 1) == 0) {
                        unsigned u = pkh(o, op);   // (d, d+1) halves
                        size_t e;
                        if (sec == 0) {
                            // Q: B-operand layout (unchanged)
                            e = abase +
                                (size_t)((((srow >> 4) * 2 + kc_d) * 4 + quad_a)) * 128 +
                                (srow & 15) * 8 + j;
                        } else {
                            // K: kappa-permuted A-block layout (r15, verified)
                            int key6 = srow & 63;
                            int mc_k = ((key6 >> 4) & 2) | ((key6 >> 2) & 1);
                            int l15k = ((key6 >> 1) & 12) | (key6 & 3);
                            e = abase + (size_t)(srow >> 6) * 4096 +
                                (mc_k * 2 + kc_d) * 512 + (quad_a * 16 + l15k) * 8 + j;
                        }
                        *(unsigned int*)(dst + e) = u;
                    }
                }
            }
        }
    } else {
        // V: fragment-major per 64-key tile (r16, verified)
#pragma unroll
        for (int mc = 0; mc < 2; mc++) {
            int key   = (m0w & 2047) + mc * 16 + quad * 4;   // rr=0 key
            int tile  = key >> 6;
            int kk2v  = (key >> 5) & 1;
            int quadk = ((key >> 3) & 3);
            int j0    = (quad & 1) * 4;
#pragma unroll
            for (int nc = 0; nc < 4; nc++) {
                float x0 = acc[mc][nc][0] + bn[nc];
                float x1 = acc[mc][nc][1] + bn[nc];
                float x2 = acc[mc][nc][2] + bn[nc];
                float x3 = acc[mc][nc][3] + bn[nc];
                unsigned u01 = pkh(x0, x1), u23 = pkh(x2, x3);
                size_t e = abase + (size_t)tile * 4096 +
                           (size_t)(((nc * 2 + kk2v) * 4 + quadk)) * 128 + l15 * 8 + j0;
                *(uint2*)(dst + e) = make_uint2(u01, u23);
            }
        }
    }
}

// ---------------- kernel 3: flash attention, f16 MFMA -------------------
// r21 state (unchanged): in-register P (kappa-K), fragment-major V,
// ones-MFMA row-sum, pkrtz pack, shfl-free defer-max vote, KVBLK=128
// dbuf, one barrier per 128 keys, LDS 32 KB, 4 blocks/CU.
__global__ __launch_bounds__(256, 4) void attn_mfma_k(
    const unsigned short* __restrict__ Qg,
    const unsigned short* __restrict__ Kg,
    const unsigned short* __restrict__ Vg,
    float* __restrict__ out)
{
    __shared__ __align__(16) unsigned short Klds[2][8192];   // K dbuf: 32 KB

    const int tid  = threadIdx.x;
    const int wave = tid >> 6;
    const int lane = tid & 63;
    const int quad = lane >> 4;
    const int l15  = lane & 15;
    const int id   = blockIdx.x;
    const int bh   = (id & 7) * 4 + ((id >> 3) & 3);   // XCD-pinned bh
    const int qt   = id >> 5;
    const int b    = bh >> 4, h = bh & 15;
    const int q0   = qt * 64 + wave * 16;
    const size_t abase = (size_t)bh * 131072;

    // Q fragments: 16 q rows per wave (B-operand, col = l15 = q)
    f16x8 qf[2];
#pragma unroll
    for (int kc = 0; kc < 2; kc++)
        qf[kc] = *(const f16x8*)(Qg + abase +
            (size_t)((((q0 >> 4) * 2 + kc) * 4 + quad)) * 128 + l15 * 8);

    // all-ones B fragment for the ps row-sum MFMA
    f16x8 ones;
#pragma unroll
    for (int i = 0; i < 8; i++) ones[i] = (_Float16)1.0f;

    f32x4 acc[4];
#pragma unroll
    for (int dc = 0; dc < 4; dc++) acc[dc] = (f32x4){0.f, 0.f, 0.f, 0.f};
    float mst = -INFINITY;
    f32x4 lst4 = (f32x4){0.f, 0.f, 0.f, 0.f};   // acc-row layout: q = quad*4+rr

    const unsigned short* kgb = Kg + abase;
    // V (fragment-major): lane base + (dc*2+kk2)*512 elem imm offsets.
    const unsigned short* vt0 = Vg + abase + quad * 128 + l15 * 8;
    const unsigned short* vt1 = vt0 + 2048;

    // one 64-key sub-tile, P never leaves registers
    auto process64 = [&](const unsigned short* ktile) {
        // V fragments (B-operand), lane-contiguous coalesced loads
        f16x8 vf[4][2];
#pragma unroll
        for (int dc = 0; dc < 2; dc++) {
            vf[dc][0]     = *(const f16x8*)(vt0 + dc * 1024);
            vf[dc][1]     = *(const f16x8*)(vt0 + dc * 1024 + 512);
            vf[dc + 2][0] = *(const f16x8*)(vt1 + dc * 1024);
            vf[dc + 2][1] = *(const f16x8*)(vt1 + dc * 1024 + 512);
        }

        // QK^T from kappa-permuted K blocks: read = base + lane*16B + imm
        const unsigned short* kb = ktile + lane * 8;
        f32x4 stt[4];
        __builtin_amdgcn_s_setprio(1);
#pragma unroll
        for (int mc = 0; mc < 4; mc++) {
            f16x8 a0 = *(const f16x8*)(kb + mc * 1024);
            f16x8 a1 = *(const f16x8*)(kb + mc * 1024 + 512);
            f32x4 s = (f32x4){0.f, 0.f, 0.f, 0.f};
            s = __builtin_amdgcn_mfma_f32_16x16x32_f16(a0, qf[0], s, 0, 0, 0);
            s = __builtin_amdgcn_mfma_f32_16x16x32_f16(a1, qf[1], s, 0, 0, 0);
            stt[mc] = s;
        }
        __builtin_amdgcn_s_setprio(0);

        // per-lane LOCAL max, balanced tree (no cross-lane shfl here)
        float t0 = fmaxf(fmaxf(stt[0][0], stt[0][1]), fmaxf(stt[0][2], stt[0][3]));
        float t1 = fmaxf(fmaxf(stt[1][0], stt[1][1]), fmaxf(stt[1][2], stt[1][3]));
        float t2 = fmaxf(fmaxf(stt[2][0], stt[2][1]), fmaxf(stt[2][2], stt[2][3]));
        float t3 = fmaxf(fmaxf(stt[3][0], stt[3][1]), fmaxf(stt[3][2], stt[3][3]));
        float mtl = fmaxf(fmaxf(t0, t1), fmaxf(t2, t3));

        // defer-max vote on the LOCAL max: equivalent outcome to the
        // cross-lane version, zero shfl in the common path
        if (!__all(mtl - mst <= 8.f)) {
            // rare path: full cross-lane reduce + rescale
            float mt = fmaxf(mtl, __shfl_xor(mtl, 16));
            mt = fmaxf(mt, __shfl_xor(mt, 32));
            float mnew = fmaxf(mst, mt);
            float alpha = __builtin_amdgcn_exp2f(mst - mnew);
            float ar[4];
#pragma unroll
            for (int rr = 0; rr < 4; rr++)
                ar[rr] = __shfl(alpha, (lane & 48) + ((lane >> 4) << 2) + rr);
#pragma unroll
            for (int rr = 0; rr < 4; rr++) lst4[rr] *= ar[rr];
#pragma unroll
            for (int dc = 0; dc < 4; dc++)
#pragma unroll
                for (int rr = 0; rr < 4; rr++) acc[dc][rr] *= ar[rr];
            mst = mnew;
        }

        // P = exp2(S - mst), pack f16 in-register via cvt_pkrtz (these
        // words ARE the PV A-fragments thanks to the kappa-permuted K)
        unsigned up[4][2];
#pragma unroll
        for (int mc = 0; mc < 4; mc++) {
            float e0 = __builtin_amdgcn_exp2f(stt[mc][0] - mst);
            float e1 = __builtin_amdgcn_exp2f(stt[mc][1] - mst);
            float e2 = __builtin_amdgcn_exp2f(stt[mc][2] - mst);
            float e3 = __builtin_amdgcn_exp2f(stt[mc][3] - mst);
            up[mc][0] = pkrtz(e0, e1);
            up[mc][1] = pkrtz(e2, e3);
        }

        union { unsigned u[4]; f16x8 h; } pc0, pc1;
        pc0.u[0] = up[0][0]; pc0.u[1] = up[0][1];
        pc0.u[2] = up[1][0]; pc0.u[3] = up[1][1];
        pc1.u[0] = up[2][0]; pc1.u[1] = up[2][1];
        pc1.u[2] = up[3][0]; pc1.u[3] = up[3][1];

        __builtin_amdgcn_s_setprio(1);
        // ps row-sum on the matrix pipe: lst4 += P . ones (acc-row layout)
        {
            f32x4 psa = (f32x4){0.f, 0.f, 0.f, 0.f};
            psa = __builtin_amdgcn_mfma_f32_16x16x32_f16(pc0.h, ones, psa, 0, 0, 0);
            psa = __builtin_amdgcn_mfma_f32_16x16x32_f16(pc1.h, ones, psa, 0, 0, 0);
            lst4 += psa;
        }
#pragma unroll
        for (int dc = 0; dc < 4; dc++) {
            f32x4 aa = acc[dc];
            aa = __builtin_amdgcn_mfma_f32_16x16x32_f16(pc0.h, vf[dc][0], aa, 0, 0, 0);
            aa = __builtin_amdgcn_mfma_f32_16x16x32_f16(pc1.h, vf[dc][1], aa, 0, 0, 0);
            acc[dc] = aa;
        }
        __builtin_amdgcn_s_setprio(0);

        vt0 += 4096;
        vt1 += 4096;
    };

    // prologue: stage K tile 0 (128 keys, 16 KB)
#pragma unroll
    for (int i = 0; i < 4; i++)
        dma16(kgb + (size_t)(tid + i * 256) * 8, &Klds[0][(tid + i * 256) * 8]);
    __syncthreads();

    int cur = 0;
    for (int it = 0; it < SS / 128; it++) {
        // prefetch next 128-key tile into the other buffer
        if (it + 1 < SS / 128) {
            const unsigned short* ks = kgb + (size_t)(it + 1) * 8192;
#pragma unroll
            for (int i = 0; i < 4; i++)
                dma16(ks + (size_t)(tid + i * 256) * 8,
                      &Klds[cur ^ 1][(tid + i * 256) * 8]);
        }

        process64(&Klds[cur][0]);
        process64(&Klds[cur][4096]);

        __syncthreads();   // all waves done with Klds[cur]; prefetch drained
        cur ^= 1;
    }

    // lst4 is already in acc-row layout: no shuffle needed
    float linv[4];
#pragma unroll
    for (int rr = 0; rr < 4; rr++) linv[rr] = 1.f / lst4[rr];
#pragma unroll
    for (int dc = 0; dc < 4; dc++)
#pragma unroll
        for (int rr = 0; rr < 4; rr++) {
            int s = q0 + quad * 4 + rr;
            out[((size_t)(b * SS + s)) * EE + h * HD + dc * 16 + l15] = acc[dc][rr] * linv[rr];
        }
}

extern "C" void kernel_launch(void* const* d_in, const int* in_sizes, int n_in,
                              void* d_out, int out_size, void* d_ws, size_t ws_size,
                              hipStream_t stream) {
    const float* X    = (const float*)d_in[0];
    const float* W    = (const float*)d_in[1];
    const float* bias = (const float*)d_in[2];
    float* out = (float*)d_out;

    float* ws = (float*)d_ws;
    float* ct = ws;                    // 65536 f32
    float* st = ws + 65536;            // 65536 f32
    unsigned short* base = (unsigned short*)(ws + 131072);
    const size_t ASZ = (size_t)32 * 131072;   // 4.19M f16 per array
    unsigned short* Qg = base;
    unsigned short* Kg = base + ASZ;
    unsigned short* Vg = base + 2 * ASZ;
    unsigned short* Xh = base + 3 * ASZ;              // 4.19M f16 (8.4 MB)
    unsigned short* Wh = Xh + (size_t)NXCHUNK * 8;    // 3.15M f16 (6.3 MB)

    tabcvt_k<<<dim3(256 + (NXCHUNK + NWCHUNK) / 256), 256, 0, stream>>>(
        X, W, Xh, Wh, ct, st);
    qkv_mfma_k<<<dim3(768), 512, 0, stream>>>(
        Xh, Wh, bias, ct, st, Qg, Kg, Vg);
    attn_mfma_k<<<dim3(1024), 256, 0, stream>>>(Qg, Kg, Vg, out);
}